// Round 7
// baseline (329.908 us; speedup 1.0000x reference)
//
#include <hip/hip_runtime.h>

// out[b,n] = sum_e c[b,n,e] * s[b,e];  B=32, N=8192, E=256, fp32.
// R6 lesson: NT config plateau at 327.0-327.6 across sweep-order, occupancy,
// grid-shape axes; only the NT bit itself ever moved the needle (-28us vs
// plain, reproduced). Final discriminator: 16 rows/iter -> half the dependent
// shuffle-tail count per byte (17 xlane ops/16 rows vs 10/8) and 2x the
// outstanding loads per wave (16 dwordx4 = 16 KiB in flight). Neutral =>
// memory-system ceiling; declare roofline.

typedef float f32x4 __attribute__((ext_vector_type(4)));

constexpr int kLogN        = 13;   // N = 8192 rows per batch
constexpr int kF4PerRow    = 64;   // E/4
constexpr int kRowsPerIter = 16;   // rows per wave per grid-stride step
constexpr int kBlocks      = 1024; // 4 blocks/CU
constexpr int kThreads     = 256;  // 4 waves/block -> 4096 waves

__device__ __forceinline__ float lane_merge(float a, float b, int sel, int off) {
    float send = sel ? a : b;
    float recv = __shfl_xor(send, off, 64);
    return (sel ? b : a) + recv;
}

__global__ __launch_bounds__(kThreads) void ctx_seg_score_kernel(
    const float* __restrict__ c,   // [B*N, E]
    const float* __restrict__ s,   // [B, E]
    float* __restrict__ out,       // [B*N]
    int total_rows)                // B*N = 262144
{
    const int lane   = threadIdx.x & 63;
    const int gwave  = (blockIdx.x * blockDim.x + threadIdx.x) >> 6;
    const int nwaves = (gridDim.x * blockDim.x) >> 6;   // 4096

    const f32x4* __restrict__ c4p = reinterpret_cast<const f32x4*>(c);
    const float4* __restrict__ s4p = reinterpret_cast<const float4*>(s);

    const int sel1 = lane & 1;
    const int sel2 = (lane >> 1) & 1;
    const int sel4 = (lane >> 2) & 1;
    const int sel8 = (lane >> 3) & 1;

    // Iteration i: 4096 waves cover a contiguous 64 MB front sweeping c.
    for (int r0 = gwave * kRowsPerIter; r0 < total_rows;
         r0 += nwaves * kRowsPerIter) {

        const int b = r0 >> kLogN;            // 16 | 8192 -> one batch per group
        const float4 s4 = s4p[b * kF4PerRow + lane];

        // 16 independent coalesced 1-KiB wave loads, non-temporal
        f32x4 a[kRowsPerIter];
        #pragma unroll
        for (int u = 0; u < kRowsPerIter; ++u)
            a[u] = __builtin_nontemporal_load(
                &c4p[(size_t)(r0 + u) * kF4PerRow + lane]);

        float p[kRowsPerIter];
        #pragma unroll
        for (int u = 0; u < kRowsPerIter; ++u)
            p[u] = fmaf(a[u].x, s4.x,
                   fmaf(a[u].y, s4.y,
                   fmaf(a[u].z, s4.z, a[u].w * s4.w)));

        // Merge tree over 4 lane bits: 15 merges -> lane l owns row (l&15)
        // summed over its 16-lane group.
        float m1[8];
        #pragma unroll
        for (int u = 0; u < 8; ++u)
            m1[u] = lane_merge(p[2*u], p[2*u+1], sel1, 1);
        float m2[4];
        #pragma unroll
        for (int u = 0; u < 4; ++u)
            m2[u] = lane_merge(m1[2*u], m1[2*u+1], sel2, 2);
        float m3[2];
        #pragma unroll
        for (int u = 0; u < 2; ++u)
            m3[u] = lane_merge(m2[2*u], m2[2*u+1], sel4, 4);
        float v = lane_merge(m3[0], m3[1], sel8, 8);

        // Butterfly over remaining lane bits: 2 shuffles.
        v += __shfl_xor(v, 16, 64);
        v += __shfl_xor(v, 32, 64);

        // lane l (l<16) holds the total for row r0+l: 64 B coalesced store.
        if (lane < kRowsPerIter)
            out[r0 + lane] = v;
    }
}

extern "C" void kernel_launch(void* const* d_in, const int* in_sizes, int n_in,
                              void* d_out, int out_size, void* d_ws, size_t ws_size,
                              hipStream_t stream) {
    const float* c = (const float*)d_in[0];
    const float* s = (const float*)d_in[1];
    float* out = (float*)d_out;

    ctx_seg_score_kernel<<<kBlocks, kThreads, 0, stream>>>(c, s, out, out_size);
}